// Round 3
// baseline (48.714 us; speedup 1.0000x reference)
//
#include <hip/hip_runtime.h>

// out[b, f] = x[b, f] * exp(diagonal[f])
// x: 8192 x 4096 f32, diagonal: 4096 f32, out: 8192 x 4096 f32.
// Memory-bound. float4-wide vectorization via native clang vector type,
// exp() hoisted (one column-quad per thread across 16 rows). Non-temporal
// stores so out doesn't evict x from L2/Infinity-Cache (x is re-read every
// replay; out is write-once).

typedef float f32x4 __attribute__((ext_vector_type(4)));

#define ROWS 8192
#define COLS 4096
#define ROW_F4 (COLS / 4)          // 1024 float4 per row
#define BLOCK 256
#define GRID_X (ROW_F4 / BLOCK)    // 4 column blocks cover a full row
#define GRID_Y 512                 // 2048 blocks total; 16 rows per thread

__global__ __launch_bounds__(BLOCK) void Diagonal_73126113181894_kernel(
    const f32x4* __restrict__ x, const float* __restrict__ diagonal,
    f32x4* __restrict__ out) {
  const int col4 = blockIdx.x * BLOCK + threadIdx.x;   // float4 column index
  // Load this thread's 4 diagonal values once, exp once, reuse for all rows.
  const f32x4 d = reinterpret_cast<const f32x4*>(diagonal)[col4];
  f32x4 e;
  e.x = expf(d.x);
  e.y = expf(d.y);
  e.z = expf(d.z);
  e.w = expf(d.w);

#pragma unroll 4
  for (int r = blockIdx.y; r < ROWS; r += GRID_Y) {
    const size_t idx = (size_t)r * ROW_F4 + col4;
    f32x4 v = x[idx];                  // regular (cacheable) load: x re-read
    v *= e;                            // across replays, keep it in L3
    __builtin_nontemporal_store(v, &out[idx]);  // streaming store (nt)
  }
}

extern "C" void kernel_launch(void* const* d_in, const int* in_sizes, int n_in,
                              void* d_out, int out_size, void* d_ws, size_t ws_size,
                              hipStream_t stream) {
  const f32x4* x = (const f32x4*)d_in[0];
  const float* diagonal = (const float*)d_in[1];
  f32x4* out = (f32x4*)d_out;

  dim3 grid(GRID_X, GRID_Y, 1);
  dim3 block(BLOCK, 1, 1);
  Diagonal_73126113181894_kernel<<<grid, block, 0, stream>>>(x, diagonal, out);
}